// Round 20
// baseline (142.764 us; speedup 1.0000x reference)
//
#include <hip/hip_runtime.h>
#include <math.h>

// GCN: out = Ahat @ (relu(Ahat @ X @ W1 + b1)) @ W2 + b2
// R14: GEMM-2 fused into mega-kernel (H1 LDS-only). 161.9us.
// R15: scan-free fixed-capacity buckets. 132.8us.
// R16: prescaled xs (pure-add gather). 131.9us.
// R17: degree sort, naive atomics -- 481us (64-address atomic serialization).
// R18: degree sort, two-level atomics -- 134.8us: build fixed but sort is
//      NEUTRAL for mega1/gather (inter-block TLP already hides tails). Verdict:
//      revert sort. mega1 at 1.4 TB/s << 3 TB/s miss wall, nothing saturated
//      -> latency-bound with only 4 row-loads in flight per node group.
// R19: sort reverted; gather loops unrolled x8 (8 loads in flight); bucket
//      list reads nontemporal (keep xs/H2b hot in L2). gather_bf measured AT
//      the miss wall (3.5 TB/s) -- at its floor.

constexpr int NN = 50000;
constexpr int NE = 640000;
constexpr int F_IN = 128;
constexpr int F_HID = 256;
constexpr int F_OUT = 128;
constexpr int CAP = 64;              // bucket capacity per node

typedef __attribute__((ext_vector_type(8))) short bf16x8;   // 8 bf16 = 4 VGPRs
typedef __attribute__((ext_vector_type(4))) float f32x4;
typedef __attribute__((ext_vector_type(8))) unsigned short u16x8;

__device__ inline unsigned short f2bf(float v) {  // RNE f32->bf16
    unsigned int u = __float_as_uint(v);
    return (unsigned short)((u + 0x7fff + ((u >> 16) & 1)) >> 16);
}
__device__ inline float bf2f(unsigned short h) {
    return __uint_as_float(((unsigned int)h) << 16);
}

// Pack W[K][N] f32 -> fragment-native bf16 hi/lo: idx = ((kt*NT+nt)*64+lane)*8+e
template <int K, int N>
__device__ inline void wpack_one(const float* __restrict__ W,
                                 unsigned short* __restrict__ hi,
                                 unsigned short* __restrict__ lo, int t) {
    constexpr int NT = N / 16;
    int lane = t & 63, nt = (t >> 6) % NT, kt = (t >> 6) / NT;
    int col = nt * 16 + (lane & 15), kg = lane >> 4;
    unsigned short hb[8], lb[8];
#pragma unroll
    for (int e = 0; e < 8; ++e) {
        int k = kt * 32 + kg * 8 + e;
        float v = W[(size_t)k * N + col];
        unsigned short h = f2bf(v);
        hb[e] = h;
        lb[e] = f2bf(v - bf2f(h));
    }
    *reinterpret_cast<u16x8*>(hi + (size_t)t * 8) = *reinterpret_cast<u16x8*>(hb);
    *reinterpret_cast<u16x8*>(lo + (size_t)t * 8) = *reinterpret_cast<u16x8*>(lb);
}

// ---- dispatch 2: bucket-fill (edges) + W packing ----
constexpr int G_FILL = (NE + 255) / 256;       // 2500
__global__ __launch_bounds__(256) void k_fill_wpack(
    const int* __restrict__ src, const int* __restrict__ dst,
    int* __restrict__ cnt, int* __restrict__ bucket,
    const float* __restrict__ W1, unsigned short* __restrict__ W1hi,
    unsigned short* __restrict__ W1lo,
    const float* __restrict__ W2, unsigned short* __restrict__ W2hi,
    unsigned short* __restrict__ W2lo) {
    if (blockIdx.x < G_FILL) {
        int e = blockIdx.x * 256 + threadIdx.x;
        if (e >= NE) return;
        int d = dst[e];
        int slot = atomicAdd(&cnt[d], 1);
        bucket[(size_t)d * CAP + slot] = src[e];
    } else {
        constexpr int T1 = (F_IN / 32) * (F_HID / 16) * 64;   // 4096
        constexpr int T2 = (F_HID / 32) * (F_OUT / 16) * 64;  // 4096
        int t = (blockIdx.x - G_FILL) * 256 + threadIdx.x;
        if (t < T1) {
            wpack_one<F_IN, F_HID>(W1, W1hi, W1lo, t);
        } else if (t < T1 + T2) {
            wpack_one<F_HID, F_OUT>(W2, W2hi, W2lo, t - T1);
        }
    }
}

// ---- dispatch 3: xs = bf16(dinv*x) + dinv[] (needs final cnt) ----
constexpr int G_CONV = NN * 16 / 256;  // 3125 (16 threads/node, 8 elems each)
__global__ __launch_bounds__(256) void k_conv_dinv(
    const int* __restrict__ cnt, const float* __restrict__ x,
    unsigned short* __restrict__ xs, float* __restrict__ dinv) {
    int gid = blockIdx.x * 256 + threadIdx.x;
    int node = gid >> 4, c = gid & 15;
    if (node >= NN) return;
    float di = rsqrtf((float)(cnt[node] + 1));
    if (c == 0) dinv[node] = di;
    float4 v0 = reinterpret_cast<const float4*>(x)[(size_t)node * 32 + c * 2];
    float4 v1 = reinterpret_cast<const float4*>(x)[(size_t)node * 32 + c * 2 + 1];
    unsigned short o[8];
    o[0] = f2bf(di * v0.x); o[1] = f2bf(di * v0.y);
    o[2] = f2bf(di * v0.z); o[3] = f2bf(di * v0.w);
    o[4] = f2bf(di * v1.x); o[5] = f2bf(di * v1.y);
    o[6] = f2bf(di * v1.z); o[7] = f2bf(di * v1.w);
    reinterpret_cast<u16x8*>(xs)[(size_t)node * 16 + c] = *reinterpret_cast<u16x8*>(o);
}

// ---- MEGA layer 1+2a: pure-add gather + GEMM-1 + GEMM-2 (H1 LDS-only) ----
// Block: 256 thr, 16 nodes. Gather unrolled x8 (8 row-loads in flight/group).
__global__ __launch_bounds__(256) void k_mega1(
    const unsigned short* __restrict__ xs, const int* __restrict__ bucket,
    const int* __restrict__ cnt, const float* __restrict__ dinv,
    const unsigned short* __restrict__ B1hi, const unsigned short* __restrict__ B1lo,
    const float* __restrict__ bias1,
    const unsigned short* __restrict__ B2hi, const unsigned short* __restrict__ B2lo,
    unsigned short* __restrict__ H2b) {
    __shared__ unsigned short Ahi_s[16][136];
    __shared__ unsigned short Alo_s[16][136];
    __shared__ unsigned short H1_s[16][264];
    __shared__ float dinv_s[16];
    const int tid = threadIdx.x;
    const int row = tid >> 4;           // node within block
    const int c = tid & 15;             // owns elems [8c, 8c+8)
    const int node = blockIdx.x * 16 + row;  // grid exact: 3125*16 = 50000

    // ---- phase 1: pure-add gather over prescaled bf16 rows ----
    const float di = dinv[node];
    if (c == 0) dinv_s[row] = di;
    const u16x8* fb = reinterpret_cast<const u16x8*>(xs);
    float acc[8];
    {
        u16x8 v = fb[(size_t)node * 16 + c];
#pragma unroll
        for (int k = 0; k < 8; ++k) acc[k] = bf2f(v[k]);
    }
    const int* blist = bucket + (size_t)node * CAP;
    const int end = cnt[node];
    int j = 0;
    for (; j + 7 < end; j += 8) {
        int s0 = __builtin_nontemporal_load(blist + j + 0);
        int s1 = __builtin_nontemporal_load(blist + j + 1);
        int s2 = __builtin_nontemporal_load(blist + j + 2);
        int s3 = __builtin_nontemporal_load(blist + j + 3);
        int s4 = __builtin_nontemporal_load(blist + j + 4);
        int s5 = __builtin_nontemporal_load(blist + j + 5);
        int s6 = __builtin_nontemporal_load(blist + j + 6);
        int s7 = __builtin_nontemporal_load(blist + j + 7);
        u16x8 r0 = fb[(size_t)s0 * 16 + c];
        u16x8 r1 = fb[(size_t)s1 * 16 + c];
        u16x8 r2 = fb[(size_t)s2 * 16 + c];
        u16x8 r3 = fb[(size_t)s3 * 16 + c];
        u16x8 r4 = fb[(size_t)s4 * 16 + c];
        u16x8 r5 = fb[(size_t)s5 * 16 + c];
        u16x8 r6 = fb[(size_t)s6 * 16 + c];
        u16x8 r7 = fb[(size_t)s7 * 16 + c];
#pragma unroll
        for (int k = 0; k < 8; ++k)
            acc[k] += ((bf2f(r0[k]) + bf2f(r1[k])) + (bf2f(r2[k]) + bf2f(r3[k])))
                    + ((bf2f(r4[k]) + bf2f(r5[k])) + (bf2f(r6[k]) + bf2f(r7[k])));
    }
    for (; j + 3 < end; j += 4) {
        int s0 = __builtin_nontemporal_load(blist + j + 0);
        int s1 = __builtin_nontemporal_load(blist + j + 1);
        int s2 = __builtin_nontemporal_load(blist + j + 2);
        int s3 = __builtin_nontemporal_load(blist + j + 3);
        u16x8 r0 = fb[(size_t)s0 * 16 + c];
        u16x8 r1 = fb[(size_t)s1 * 16 + c];
        u16x8 r2 = fb[(size_t)s2 * 16 + c];
        u16x8 r3 = fb[(size_t)s3 * 16 + c];
#pragma unroll
        for (int k = 0; k < 8; ++k)
            acc[k] += (bf2f(r0[k]) + bf2f(r1[k])) + (bf2f(r2[k]) + bf2f(r3[k]));
    }
    for (; j < end; ++j) {
        int s = __builtin_nontemporal_load(blist + j);
        u16x8 r = fb[(size_t)s * 16 + c];
#pragma unroll
        for (int k = 0; k < 8; ++k) acc[k] += bf2f(r[k]);
    }
    // split agg (f32-grade) to LDS hi/lo; outer dinv applied here
    {
        unsigned short hb[8], lb[8];
#pragma unroll
        for (int k = 0; k < 8; ++k) {
            float v = acc[k] * di;
            hb[k] = f2bf(v);
            lb[k] = f2bf(v - bf2f(hb[k]));
        }
        *reinterpret_cast<u16x8*>(&Ahi_s[row][c * 8]) = *reinterpret_cast<u16x8*>(hb);
        *reinterpret_cast<u16x8*>(&Alo_s[row][c * 8]) = *reinterpret_cast<u16x8*>(lb);
    }
    __syncthreads();

    // ---- phase 2: GEMM-1 (wave wv: 16 rows x 64 cols), 3-pass ----
    const int lane = tid & 63;
    const int wv = tid >> 6;
    const int r16 = lane & 15;
    const int kg = lane >> 4;
    const int ccol = lane & 15;
    const int crow0 = (lane >> 4) * 4;
    {
        f32x4 acc2[4];
#pragma unroll
        for (int ct = 0; ct < 4; ++ct) acc2[ct] = (f32x4){0.f, 0.f, 0.f, 0.f};
        const unsigned short* pb_hi = B1hi + (size_t)lane * 8;
        const unsigned short* pb_lo = B1lo + (size_t)lane * 8;
#pragma unroll
        for (int kt = 0; kt < 4; ++kt) {
            bf16x8 ah = *reinterpret_cast<const bf16x8*>(&Ahi_s[r16][kt * 32 + kg * 8]);
            bf16x8 al = *reinterpret_cast<const bf16x8*>(&Alo_s[r16][kt * 32 + kg * 8]);
#pragma unroll
            for (int ct = 0; ct < 4; ++ct) {
                const int nt = wv * 4 + ct;
                bf16x8 bh = *reinterpret_cast<const bf16x8*>(pb_hi + (size_t)(kt * 16 + nt) * 512);
                bf16x8 bl = *reinterpret_cast<const bf16x8*>(pb_lo + (size_t)(kt * 16 + nt) * 512);
                acc2[ct] = __builtin_amdgcn_mfma_f32_16x16x32_bf16(ah, bh, acc2[ct], 0, 0, 0);
                acc2[ct] = __builtin_amdgcn_mfma_f32_16x16x32_bf16(ah, bl, acc2[ct], 0, 0, 0);
                acc2[ct] = __builtin_amdgcn_mfma_f32_16x16x32_bf16(al, bh, acc2[ct], 0, 0, 0);
            }
        }
        // epilogue: bias + relu -> bf16 H1 tile in LDS
#pragma unroll
        for (int ct = 0; ct < 4; ++ct) {
            int col = (wv * 4 + ct) * 16 + ccol;
            float bv = bias1[col];
#pragma unroll
            for (int i = 0; i < 4; ++i) {
                float v = fmaxf(acc2[ct][i] + bv, 0.f);
                H1_s[crow0 + i][col] = f2bf(v);
            }
        }
    }
    __syncthreads();

    // ---- phase 3: GEMM-2 (wave wv: 16 rows x 32 cols), 2-pass, prescale ----
    {
        f32x4 acc3[2];
        acc3[0] = (f32x4){0.f, 0.f, 0.f, 0.f};
        acc3[1] = (f32x4){0.f, 0.f, 0.f, 0.f};
        const unsigned short* pb_hi = B2hi + (size_t)lane * 8;
        const unsigned short* pb_lo = B2lo + (size_t)lane * 8;
#pragma unroll
        for (int kt = 0; kt < 8; ++kt) {
            bf16x8 a = *reinterpret_cast<const bf16x8*>(&H1_s[r16][kt * 32 + kg * 8]);
#pragma unroll
            for (int ct = 0; ct < 2; ++ct) {
                const int nt = wv * 2 + ct;
                bf16x8 bh = *reinterpret_cast<const bf16x8*>(pb_hi + (size_t)(kt * 8 + nt) * 512);
                bf16x8 bl = *reinterpret_cast<const bf16x8*>(pb_lo + (size_t)(kt * 8 + nt) * 512);
                acc3[ct] = __builtin_amdgcn_mfma_f32_16x16x32_bf16(a, bh, acc3[ct], 0, 0, 0);
                acc3[ct] = __builtin_amdgcn_mfma_f32_16x16x32_bf16(a, bl, acc3[ct], 0, 0, 0);
            }
        }
        // epilogue: dinv prescale -> bf16 H2b
#pragma unroll
        for (int ct = 0; ct < 2; ++ct) {
            int col = (wv * 2 + ct) * 16 + ccol;
#pragma unroll
            for (int i = 0; i < 4; ++i) {
                float v = acc3[ct][i] * dinv_s[crow0 + i];
                H2b[(size_t)(blockIdx.x * 16 + crow0 + i) * F_OUT + col] = f2bf(v);
            }
        }
    }
}

// Layer-2 gather over bf16 rows (prescaled): out = dinv[v]*(H[v] + sum H[s]) + b2
__global__ __launch_bounds__(256) void k_gather_bf(
    const unsigned short* __restrict__ feat, const int* __restrict__ bucket,
    const int* __restrict__ cnt, const float* __restrict__ dinv,
    const float* __restrict__ bias, float* __restrict__ out_f) {
    int node = blockIdx.x * 16 + (threadIdx.x >> 4);
    int c = threadIdx.x & 15;          // owns feats [8c, 8c+8)
    if (node >= NN) return;
    const u16x8* fb = reinterpret_cast<const u16x8*>(feat);  // 16 chunks/row
    float acc[8];
    {
        u16x8 v = fb[(size_t)node * 16 + c];
#pragma unroll
        for (int k = 0; k < 8; ++k) acc[k] = bf2f(v[k]);
    }
    const int* blist = bucket + (size_t)node * CAP;
    const int end = cnt[node];
    int j = 0;
    for (; j + 7 < end; j += 8) {
        int s0 = __builtin_nontemporal_load(blist + j + 0);
        int s1 = __builtin_nontemporal_load(blist + j + 1);
        int s2 = __builtin_nontemporal_load(blist + j + 2);
        int s3 = __builtin_nontemporal_load(blist + j + 3);
        int s4 = __builtin_nontemporal_load(blist + j + 4);
        int s5 = __builtin_nontemporal_load(blist + j + 5);
        int s6 = __builtin_nontemporal_load(blist + j + 6);
        int s7 = __builtin_nontemporal_load(blist + j + 7);
        u16x8 r0 = fb[(size_t)s0 * 16 + c];
        u16x8 r1 = fb[(size_t)s1 * 16 + c];
        u16x8 r2 = fb[(size_t)s2 * 16 + c];
        u16x8 r3 = fb[(size_t)s3 * 16 + c];
        u16x8 r4 = fb[(size_t)s4 * 16 + c];
        u16x8 r5 = fb[(size_t)s5 * 16 + c];
        u16x8 r6 = fb[(size_t)s6 * 16 + c];
        u16x8 r7 = fb[(size_t)s7 * 16 + c];
#pragma unroll
        for (int k = 0; k < 8; ++k)
            acc[k] += ((bf2f(r0[k]) + bf2f(r1[k])) + (bf2f(r2[k]) + bf2f(r3[k])))
                    + ((bf2f(r4[k]) + bf2f(r5[k])) + (bf2f(r6[k]) + bf2f(r7[k])));
    }
    for (; j + 3 < end; j += 4) {
        int s0 = __builtin_nontemporal_load(blist + j + 0);
        int s1 = __builtin_nontemporal_load(blist + j + 1);
        int s2 = __builtin_nontemporal_load(blist + j + 2);
        int s3 = __builtin_nontemporal_load(blist + j + 3);
        u16x8 r0 = fb[(size_t)s0 * 16 + c];
        u16x8 r1 = fb[(size_t)s1 * 16 + c];
        u16x8 r2 = fb[(size_t)s2 * 16 + c];
        u16x8 r3 = fb[(size_t)s3 * 16 + c];
#pragma unroll
        for (int k = 0; k < 8; ++k)
            acc[k] += (bf2f(r0[k]) + bf2f(r1[k])) + (bf2f(r2[k]) + bf2f(r3[k]));
    }
    for (; j < end; ++j) {
        int s = __builtin_nontemporal_load(blist + j);
        u16x8 r = fb[(size_t)s * 16 + c];
#pragma unroll
        for (int k = 0; k < 8; ++k) acc[k] += bf2f(r[k]);
    }
    float di = dinv[node];
    float4 o0, o1;
    const float4* b4 = reinterpret_cast<const float4*>(bias);
    float4 b0 = b4[c * 2], b1 = b4[c * 2 + 1];
    o0.x = acc[0] * di + b0.x; o0.y = acc[1] * di + b0.y;
    o0.z = acc[2] * di + b0.z; o0.w = acc[3] * di + b0.w;
    o1.x = acc[4] * di + b1.x; o1.y = acc[5] * di + b1.y;
    o1.z = acc[6] * di + b1.z; o1.w = acc[7] * di + b1.w;
    float4* o4 = reinterpret_cast<float4*>(out_f);
    o4[(size_t)node * 32 + c * 2] = o0;
    o4[(size_t)node * 32 + c * 2 + 1] = o1;
}

extern "C" void kernel_launch(void* const* d_in, const int* in_sizes, int n_in,
                              void* d_out, int out_size, void* d_ws, size_t ws_size,
                              hipStream_t stream) {
    const float* x  = (const float*)d_in[0];
    const int*   ei = (const int*)d_in[1];
    const float* W1 = (const float*)d_in[2];
    const float* b1 = (const float*)d_in[3];
    const float* W2 = (const float*)d_in[4];
    const float* b2 = (const float*)d_in[5];
    float* out = (float*)d_out;

    const int* src = ei;
    const int* dst = ei + NE;

    // workspace layout (256-aligned):
    char* ws = (char*)d_ws;
    int*   cnt  = (int*)ws;                                  // 200 KB
    float* dinv = (float*)(ws + 262144);                     // 200 KB
    unsigned short* W1hi = (unsigned short*)(ws + 524288);   // 64 KB each
    unsigned short* W1lo = (unsigned short*)(ws + 589824);
    unsigned short* W2hi = (unsigned short*)(ws + 655360);
    unsigned short* W2lo = (unsigned short*)(ws + 720896);
    int*   bucket  = (int*)(ws + 1048576);                   // 12.8 MB
    unsigned short* xs   = (unsigned short*)(ws + 14680064); // 12.8 MB (bf16 dinv*x)
    unsigned short* H2b  = (unsigned short*)(ws + 28311552); // 12.8 MB (bf16 Hs2)

    constexpr int BT = 256;
    const int gG = NN / 16;              // 3125 (exact)

    // build: zero counts; fill buckets + pack W; prescale-convert x + dinv
    hipMemsetAsync(cnt, 0, NN * sizeof(int), stream);
    k_fill_wpack<<<G_FILL + 32, BT, 0, stream>>>(
        src, dst, cnt, bucket, W1, W1hi, W1lo, W2, W2hi, W2lo);
    k_conv_dinv<<<G_CONV, BT, 0, stream>>>(cnt, x, xs, dinv);

    // MEGA: Hs2 = bf16(dinv * (relu((Ahat x) @ W1 + b1) @ W2))
    k_mega1<<<gG, BT, 0, stream>>>(xs, bucket, cnt, dinv,
                                   W1hi, W1lo, b1, W2hi, W2lo, H2b);
    // out = dinv[v]*(Hs2[v] + sum Hs2[s]) + b2
    k_gather_bf<<<gG, BT, 0, stream>>>(H2b, bucket, cnt, dinv, b2, out);
}

// Round 21
// 128.475 us; speedup vs baseline: 1.1112x; 1.1112x over previous
//
#include <hip/hip_runtime.h>
#include <math.h>

// GCN: out = Ahat @ (relu(Ahat @ X @ W1 + b1)) @ W2 + b2
// R14: GEMM-2 fused into mega-kernel (H1 LDS-only). 161.9us.
// R15: scan-free fixed-capacity buckets. 132.8us.
// R16: prescaled xs (pure-add gather). 131.9us.  <-- BEST
// R17: degree sort, naive atomics -- 481us (atomic serialization).
// R18: degree sort, two-level atomics -- 134.8us: sort NEUTRAL (TLP already
//      hides degree tails). Reverted.
// R19: x8 unroll + nontemporal -- 142.8us REGRESSION: VGPR 36->52 dropped
//      occupancy 58->35%; TLP loss > ILP gain. Reverted.
// R20: exact R16 config + int4 vectorized bucket-index loads (blist is 16B
//      aligned; 4 index loads -> 1, VGPR-neutral).

constexpr int NN = 50000;
constexpr int NE = 640000;
constexpr int F_IN = 128;
constexpr int F_HID = 256;
constexpr int F_OUT = 128;
constexpr int CAP = 64;              // bucket capacity per node

typedef __attribute__((ext_vector_type(8))) short bf16x8;   // 8 bf16 = 4 VGPRs
typedef __attribute__((ext_vector_type(4))) float f32x4;
typedef __attribute__((ext_vector_type(8))) unsigned short u16x8;

__device__ inline unsigned short f2bf(float v) {  // RNE f32->bf16
    unsigned int u = __float_as_uint(v);
    return (unsigned short)((u + 0x7fff + ((u >> 16) & 1)) >> 16);
}
__device__ inline float bf2f(unsigned short h) {
    return __uint_as_float(((unsigned int)h) << 16);
}

// Pack W[K][N] f32 -> fragment-native bf16 hi/lo: idx = ((kt*NT+nt)*64+lane)*8+e
template <int K, int N>
__device__ inline void wpack_one(const float* __restrict__ W,
                                 unsigned short* __restrict__ hi,
                                 unsigned short* __restrict__ lo, int t) {
    constexpr int NT = N / 16;
    int lane = t & 63, nt = (t >> 6) % NT, kt = (t >> 6) / NT;
    int col = nt * 16 + (lane & 15), kg = lane >> 4;
    unsigned short hb[8], lb[8];
#pragma unroll
    for (int e = 0; e < 8; ++e) {
        int k = kt * 32 + kg * 8 + e;
        float v = W[(size_t)k * N + col];
        unsigned short h = f2bf(v);
        hb[e] = h;
        lb[e] = f2bf(v - bf2f(h));
    }
    *reinterpret_cast<u16x8*>(hi + (size_t)t * 8) = *reinterpret_cast<u16x8*>(hb);
    *reinterpret_cast<u16x8*>(lo + (size_t)t * 8) = *reinterpret_cast<u16x8*>(lb);
}

// ---- dispatch 2: bucket-fill (edges) + W packing ----
constexpr int G_FILL = (NE + 255) / 256;       // 2500
__global__ __launch_bounds__(256) void k_fill_wpack(
    const int* __restrict__ src, const int* __restrict__ dst,
    int* __restrict__ cnt, int* __restrict__ bucket,
    const float* __restrict__ W1, unsigned short* __restrict__ W1hi,
    unsigned short* __restrict__ W1lo,
    const float* __restrict__ W2, unsigned short* __restrict__ W2hi,
    unsigned short* __restrict__ W2lo) {
    if (blockIdx.x < G_FILL) {
        int e = blockIdx.x * 256 + threadIdx.x;
        if (e >= NE) return;
        int d = dst[e];
        int slot = atomicAdd(&cnt[d], 1);
        bucket[(size_t)d * CAP + slot] = src[e];
    } else {
        constexpr int T1 = (F_IN / 32) * (F_HID / 16) * 64;   // 4096
        constexpr int T2 = (F_HID / 32) * (F_OUT / 16) * 64;  // 4096
        int t = (blockIdx.x - G_FILL) * 256 + threadIdx.x;
        if (t < T1) {
            wpack_one<F_IN, F_HID>(W1, W1hi, W1lo, t);
        } else if (t < T1 + T2) {
            wpack_one<F_HID, F_OUT>(W2, W2hi, W2lo, t - T1);
        }
    }
}

// ---- dispatch 3: xs = bf16(dinv*x) + dinv[] (needs final cnt) ----
constexpr int G_CONV = NN * 16 / 256;  // 3125 (16 threads/node, 8 elems each)
__global__ __launch_bounds__(256) void k_conv_dinv(
    const int* __restrict__ cnt, const float* __restrict__ x,
    unsigned short* __restrict__ xs, float* __restrict__ dinv) {
    int gid = blockIdx.x * 256 + threadIdx.x;
    int node = gid >> 4, c = gid & 15;
    if (node >= NN) return;
    float di = rsqrtf((float)(cnt[node] + 1));
    if (c == 0) dinv[node] = di;
    float4 v0 = reinterpret_cast<const float4*>(x)[(size_t)node * 32 + c * 2];
    float4 v1 = reinterpret_cast<const float4*>(x)[(size_t)node * 32 + c * 2 + 1];
    unsigned short o[8];
    o[0] = f2bf(di * v0.x); o[1] = f2bf(di * v0.y);
    o[2] = f2bf(di * v0.z); o[3] = f2bf(di * v0.w);
    o[4] = f2bf(di * v1.x); o[5] = f2bf(di * v1.y);
    o[6] = f2bf(di * v1.z); o[7] = f2bf(di * v1.w);
    reinterpret_cast<u16x8*>(xs)[(size_t)node * 16 + c] = *reinterpret_cast<u16x8*>(o);
}

// ---- MEGA layer 1+2a: pure-add gather + GEMM-1 + GEMM-2 (H1 LDS-only) ----
// Block: 256 thr, 16 nodes; R16 shape; int4 index loads.
__global__ __launch_bounds__(256) void k_mega1(
    const unsigned short* __restrict__ xs, const int* __restrict__ bucket,
    const int* __restrict__ cnt, const float* __restrict__ dinv,
    const unsigned short* __restrict__ B1hi, const unsigned short* __restrict__ B1lo,
    const float* __restrict__ bias1,
    const unsigned short* __restrict__ B2hi, const unsigned short* __restrict__ B2lo,
    unsigned short* __restrict__ H2b) {
    __shared__ unsigned short Ahi_s[16][136];
    __shared__ unsigned short Alo_s[16][136];
    __shared__ unsigned short H1_s[16][264];
    __shared__ float dinv_s[16];
    const int tid = threadIdx.x;
    const int row = tid >> 4;           // node within block
    const int c = tid & 15;             // owns elems [8c, 8c+8)
    const int node = blockIdx.x * 16 + row;  // grid exact: 3125*16 = 50000

    // ---- phase 1: pure-add gather over prescaled bf16 rows ----
    const float di = dinv[node];
    if (c == 0) dinv_s[row] = di;
    const u16x8* fb = reinterpret_cast<const u16x8*>(xs);
    float acc[8];
    {
        u16x8 v = fb[(size_t)node * 16 + c];
#pragma unroll
        for (int k = 0; k < 8; ++k) acc[k] = bf2f(v[k]);
    }
    const int* blist = bucket + (size_t)node * CAP;
    const int end = cnt[node];
    int j = 0;
    for (; j + 3 < end; j += 4) {
        int4 s4 = *reinterpret_cast<const int4*>(blist + j);  // 16B-aligned
        u16x8 r0 = fb[(size_t)s4.x * 16 + c];
        u16x8 r1 = fb[(size_t)s4.y * 16 + c];
        u16x8 r2 = fb[(size_t)s4.z * 16 + c];
        u16x8 r3 = fb[(size_t)s4.w * 16 + c];
#pragma unroll
        for (int k = 0; k < 8; ++k)
            acc[k] += (bf2f(r0[k]) + bf2f(r1[k])) + (bf2f(r2[k]) + bf2f(r3[k]));
    }
    for (; j < end; ++j) {
        u16x8 r = fb[(size_t)blist[j] * 16 + c];
#pragma unroll
        for (int k = 0; k < 8; ++k) acc[k] += bf2f(r[k]);
    }
    // split agg (f32-grade) to LDS hi/lo; outer dinv applied here
    {
        unsigned short hb[8], lb[8];
#pragma unroll
        for (int k = 0; k < 8; ++k) {
            float v = acc[k] * di;
            hb[k] = f2bf(v);
            lb[k] = f2bf(v - bf2f(hb[k]));
        }
        *reinterpret_cast<u16x8*>(&Ahi_s[row][c * 8]) = *reinterpret_cast<u16x8*>(hb);
        *reinterpret_cast<u16x8*>(&Alo_s[row][c * 8]) = *reinterpret_cast<u16x8*>(lb);
    }
    __syncthreads();

    // ---- phase 2: GEMM-1 (wave wv: 16 rows x 64 cols), 3-pass ----
    const int lane = tid & 63;
    const int wv = tid >> 6;
    const int r16 = lane & 15;
    const int kg = lane >> 4;
    const int ccol = lane & 15;
    const int crow0 = (lane >> 4) * 4;
    {
        f32x4 acc2[4];
#pragma unroll
        for (int ct = 0; ct < 4; ++ct) acc2[ct] = (f32x4){0.f, 0.f, 0.f, 0.f};
        const unsigned short* pb_hi = B1hi + (size_t)lane * 8;
        const unsigned short* pb_lo = B1lo + (size_t)lane * 8;
#pragma unroll
        for (int kt = 0; kt < 4; ++kt) {
            bf16x8 ah = *reinterpret_cast<const bf16x8*>(&Ahi_s[r16][kt * 32 + kg * 8]);
            bf16x8 al = *reinterpret_cast<const bf16x8*>(&Alo_s[r16][kt * 32 + kg * 8]);
#pragma unroll
            for (int ct = 0; ct < 4; ++ct) {
                const int nt = wv * 4 + ct;
                bf16x8 bh = *reinterpret_cast<const bf16x8*>(pb_hi + (size_t)(kt * 16 + nt) * 512);
                bf16x8 bl = *reinterpret_cast<const bf16x8*>(pb_lo + (size_t)(kt * 16 + nt) * 512);
                acc2[ct] = __builtin_amdgcn_mfma_f32_16x16x32_bf16(ah, bh, acc2[ct], 0, 0, 0);
                acc2[ct] = __builtin_amdgcn_mfma_f32_16x16x32_bf16(ah, bl, acc2[ct], 0, 0, 0);
                acc2[ct] = __builtin_amdgcn_mfma_f32_16x16x32_bf16(al, bh, acc2[ct], 0, 0, 0);
            }
        }
        // epilogue: bias + relu -> bf16 H1 tile in LDS
#pragma unroll
        for (int ct = 0; ct < 4; ++ct) {
            int col = (wv * 4 + ct) * 16 + ccol;
            float bv = bias1[col];
#pragma unroll
            for (int i = 0; i < 4; ++i) {
                float v = fmaxf(acc2[ct][i] + bv, 0.f);
                H1_s[crow0 + i][col] = f2bf(v);
            }
        }
    }
    __syncthreads();

    // ---- phase 3: GEMM-2 (wave wv: 16 rows x 32 cols), 2-pass, prescale ----
    {
        f32x4 acc3[2];
        acc3[0] = (f32x4){0.f, 0.f, 0.f, 0.f};
        acc3[1] = (f32x4){0.f, 0.f, 0.f, 0.f};
        const unsigned short* pb_hi = B2hi + (size_t)lane * 8;
        const unsigned short* pb_lo = B2lo + (size_t)lane * 8;
#pragma unroll
        for (int kt = 0; kt < 8; ++kt) {
            bf16x8 a = *reinterpret_cast<const bf16x8*>(&H1_s[r16][kt * 32 + kg * 8]);
#pragma unroll
            for (int ct = 0; ct < 2; ++ct) {
                const int nt = wv * 2 + ct;
                bf16x8 bh = *reinterpret_cast<const bf16x8*>(pb_hi + (size_t)(kt * 8 + nt) * 512);
                bf16x8 bl = *reinterpret_cast<const bf16x8*>(pb_lo + (size_t)(kt * 8 + nt) * 512);
                acc3[ct] = __builtin_amdgcn_mfma_f32_16x16x32_bf16(a, bh, acc3[ct], 0, 0, 0);
                acc3[ct] = __builtin_amdgcn_mfma_f32_16x16x32_bf16(a, bl, acc3[ct], 0, 0, 0);
            }
        }
        // epilogue: dinv prescale -> bf16 H2b
#pragma unroll
        for (int ct = 0; ct < 2; ++ct) {
            int col = (wv * 2 + ct) * 16 + ccol;
#pragma unroll
            for (int i = 0; i < 4; ++i) {
                float v = acc3[ct][i] * dinv_s[crow0 + i];
                H2b[(size_t)(blockIdx.x * 16 + crow0 + i) * F_OUT + col] = f2bf(v);
            }
        }
    }
}

// Layer-2 gather over bf16 rows (prescaled): out = dinv[v]*(H[v] + sum H[s]) + b2
__global__ __launch_bounds__(256) void k_gather_bf(
    const unsigned short* __restrict__ feat, const int* __restrict__ bucket,
    const int* __restrict__ cnt, const float* __restrict__ dinv,
    const float* __restrict__ bias, float* __restrict__ out_f) {
    int node = blockIdx.x * 16 + (threadIdx.x >> 4);
    int c = threadIdx.x & 15;          // owns feats [8c, 8c+8)
    if (node >= NN) return;
    const u16x8* fb = reinterpret_cast<const u16x8*>(feat);  // 16 chunks/row
    float acc[8];
    {
        u16x8 v = fb[(size_t)node * 16 + c];
#pragma unroll
        for (int k = 0; k < 8; ++k) acc[k] = bf2f(v[k]);
    }
    const int* blist = bucket + (size_t)node * CAP;
    const int end = cnt[node];
    int j = 0;
    for (; j + 3 < end; j += 4) {
        int4 s4 = *reinterpret_cast<const int4*>(blist + j);  // 16B-aligned
        u16x8 r0 = fb[(size_t)s4.x * 16 + c];
        u16x8 r1 = fb[(size_t)s4.y * 16 + c];
        u16x8 r2 = fb[(size_t)s4.z * 16 + c];
        u16x8 r3 = fb[(size_t)s4.w * 16 + c];
#pragma unroll
        for (int k = 0; k < 8; ++k)
            acc[k] += (bf2f(r0[k]) + bf2f(r1[k])) + (bf2f(r2[k]) + bf2f(r3[k]));
    }
    for (; j < end; ++j) {
        u16x8 r = fb[(size_t)blist[j] * 16 + c];
#pragma unroll
        for (int k = 0; k < 8; ++k) acc[k] += bf2f(r[k]);
    }
    float di = dinv[node];
    float4 o0, o1;
    const float4* b4 = reinterpret_cast<const float4*>(bias);
    float4 b0 = b4[c * 2], b1 = b4[c * 2 + 1];
    o0.x = acc[0] * di + b0.x; o0.y = acc[1] * di + b0.y;
    o0.z = acc[2] * di + b0.z; o0.w = acc[3] * di + b0.w;
    o1.x = acc[4] * di + b1.x; o1.y = acc[5] * di + b1.y;
    o1.z = acc[6] * di + b1.z; o1.w = acc[7] * di + b1.w;
    float4* o4 = reinterpret_cast<float4*>(out_f);
    o4[(size_t)node * 32 + c * 2] = o0;
    o4[(size_t)node * 32 + c * 2 + 1] = o1;
}

extern "C" void kernel_launch(void* const* d_in, const int* in_sizes, int n_in,
                              void* d_out, int out_size, void* d_ws, size_t ws_size,
                              hipStream_t stream) {
    const float* x  = (const float*)d_in[0];
    const int*   ei = (const int*)d_in[1];
    const float* W1 = (const float*)d_in[2];
    const float* b1 = (const float*)d_in[3];
    const float* W2 = (const float*)d_in[4];
    const float* b2 = (const float*)d_in[5];
    float* out = (float*)d_out;

    const int* src = ei;
    const int* dst = ei + NE;

    // workspace layout (256-aligned):
    char* ws = (char*)d_ws;
    int*   cnt  = (int*)ws;                                  // 200 KB
    float* dinv = (float*)(ws + 262144);                     // 200 KB
    unsigned short* W1hi = (unsigned short*)(ws + 524288);   // 64 KB each
    unsigned short* W1lo = (unsigned short*)(ws + 589824);
    unsigned short* W2hi = (unsigned short*)(ws + 655360);
    unsigned short* W2lo = (unsigned short*)(ws + 720896);
    int*   bucket  = (int*)(ws + 1048576);                   // 12.8 MB
    unsigned short* xs   = (unsigned short*)(ws + 14680064); // 12.8 MB (bf16 dinv*x)
    unsigned short* H2b  = (unsigned short*)(ws + 28311552); // 12.8 MB (bf16 Hs2)

    constexpr int BT = 256;
    const int gG = NN / 16;              // 3125 (exact)

    // build: zero counts; fill buckets + pack W; prescale-convert x + dinv
    hipMemsetAsync(cnt, 0, NN * sizeof(int), stream);
    k_fill_wpack<<<G_FILL + 32, BT, 0, stream>>>(
        src, dst, cnt, bucket, W1, W1hi, W1lo, W2, W2hi, W2lo);
    k_conv_dinv<<<G_CONV, BT, 0, stream>>>(cnt, x, xs, dinv);

    // MEGA: Hs2 = bf16(dinv * (relu((Ahat x) @ W1 + b1) @ W2))
    k_mega1<<<gG, BT, 0, stream>>>(xs, bucket, cnt, dinv,
                                   W1hi, W1lo, b1, W2hi, W2lo, H2b);
    // out = dinv[v]*(Hs2[v] + sum Hs2[s]) + b2
    k_gather_bf<<<gG, BT, 0, stream>>>(H2b, bucket, cnt, dinv, b2, out);
}